// Round 4
// baseline (707.550 us; speedup 1.0000x reference)
//
#include <hip/hip_runtime.h>
#include <stdint.h>

#define N_NODES 100000
#define N_EDGES 1000000
#define DIM 256

typedef __attribute__((ext_vector_type(8))) short short8;   // bf16 A/B frag (4 VGPR)
typedef __attribute__((ext_vector_type(4))) float f32x4;    // fp32 C/D frag

__device__ inline float b2f(unsigned short u) {
    union { unsigned int i; float f; } v; v.i = ((unsigned int)u) << 16; return v.f;
}
__device__ inline unsigned short f2b(float f) {   // round-to-nearest-even
    union { float f; unsigned int i; } v; v.f = f;
    unsigned int u = v.i;
    return (unsigned short)((u + 0x7FFFu + ((u >> 16) & 1u)) >> 16);
}

// ---------------- workspace layout (bytes) ----------------
// deg     u32 N        @ 0
// cursor  u32 N        @ 400000
// counter u32 1        @ 800000
// dinv    f32 N        @ 800256
// start   u32 N        @ 1200384
// col     i32 E        @ 1600512
// Wt1     bf16 256x256 @ 5600512   (n-major, k contiguous)
// Wt2     bf16 256x256 @ 5731584
// xs      bf16 N*256   @ 5862656    (dinv-prescaled features, layer-1 input)
// z1s     bf16 N*256   @ 57062656   (dinv-prescaled layer-1 output)

__global__ void k_zero(uint32_t* __restrict__ p, int n) {
    int i = blockIdx.x * blockDim.x + threadIdx.x;
    int stride = gridDim.x * blockDim.x;
    for (; i < n; i += stride) p[i] = 0u;
}

__global__ void k_count(const int* __restrict__ dst, uint32_t* __restrict__ deg) {
    int e = blockIdx.x * blockDim.x + threadIdx.x;
    if (e < N_EDGES) {
        unsigned d = (unsigned)dst[e];
        if (d < N_NODES) atomicAdd(&deg[d], 1u);
    }
}

__global__ void k_dinv_start(const uint32_t* __restrict__ deg,
                             float* __restrict__ dinv,
                             uint32_t* __restrict__ start,
                             uint32_t* __restrict__ counter) {
    int n = blockIdx.x * blockDim.x + threadIdx.x;
    int lane = threadIdx.x & 63;
    int d = (n < N_NODES) ? (int)deg[n] : 0;
    int v = d;
    #pragma unroll
    for (int off = 1; off < 64; off <<= 1) {
        int t = __shfl_up(v, off, 64);
        if (lane >= off) v += t;
    }
    int total = __shfl(v, 63, 64);
    int base = 0;
    if (lane == 63) base = (int)atomicAdd(counter, (uint32_t)total);
    base = __shfl(base, 63, 64);
    if (n < N_NODES) {
        start[n] = (uint32_t)(base + v - d);   // exclusive
        dinv[n]  = rsqrtf((float)(d + 1));     // +1 self-loop
    }
}

__global__ void k_fill(const int* __restrict__ src, const int* __restrict__ dst,
                       const uint32_t* __restrict__ start,
                       uint32_t* __restrict__ cursor, int* __restrict__ col) {
    int e = blockIdx.x * blockDim.x + threadIdx.x;
    if (e < N_EDGES) {
        unsigned d = (unsigned)dst[e];
        unsigned s = (unsigned)src[e];
        if (d < N_NODES && s < N_NODES) {
            uint32_t p = atomicAdd(&cursor[d], 1u);
            col[start[d] + p] = (int)s;
        }
    }
}

// W (k-major, [k][n] fp32) -> Wt (n-major, [n][k] bf16)
__global__ void k_pack_w(const float* __restrict__ W, unsigned short* __restrict__ Wt) {
    int n = blockIdx.x, k = threadIdx.x;
    Wt[n * 256 + k] = f2b(W[k * 256 + n]);
}

// xs[row] = bf16( dinv[row] * x[row] )  (4 elems/thread; 64 threads/row)
__global__ void k_cvt_x(const float* __restrict__ x, const float* __restrict__ dinv,
                        unsigned short* __restrict__ xs) {
    int i = blockIdx.x * 256 + threadIdx.x;   // float4 index
    int row = i >> 6;                          // 64 float4 per row
    float di = dinv[row];
    float4 v = ((const float4*)x)[i];
    ushort4 o;
    o.x = f2b(di * v.x); o.y = f2b(di * v.y); o.z = f2b(di * v.z); o.w = f2b(di * v.w);
    ((ushort4*)xs)[i] = o;
}

// Fused per layer: block = 64 nodes.
// Phase 1 (gather -> LDS): wave w gathers nodes [rowBase+16w, +16); per node,
// lane = 4 channels (ushort4 = 8 B/lane), rows are dinv-prescaled so the edge
// loop is a pure row-sum, unrolled x4 for 4 outstanding 512 B fetches/wave.
// Result agg row = dinv[n]*(rows[n] + sum rows[col]) packed bf16 into As.
// Phase 2 (MFMA): C[64x256] = A_tile @ W; wave w -> cols [64w, 64w+64).
// B frags from packed global Wt[n][k] (128 KB, L1/L2-hot).
// Epilogue: Cb!=null -> bf16 dinv[row]*relu(.+b) (layer-2 input);
//           else fp32 relu(.+b) to Cf (final output).
__global__ __launch_bounds__(256) void k_fused(
        const unsigned short* __restrict__ rows, const unsigned short* __restrict__ Wt,
        const float* __restrict__ bias, const float* __restrict__ dinv,
        const uint32_t* __restrict__ start, const uint32_t* __restrict__ deg,
        const int* __restrict__ col,
        unsigned short* __restrict__ Cb, float* __restrict__ Cf) {
    __shared__ unsigned short As[64 * 264];   // 33792 B (row stride 528 B)
    int tid = threadIdx.x;
    int wave = tid >> 6, lane = tid & 63;
    int rowBase = blockIdx.x * 64;

    // ---- phase 1: gather 16 nodes per wave into As ----
    const ushort4* r4 = (const ushort4*)rows;
    for (int i = 0; i < 16; ++i) {
        int r = wave * 16 + i;
        int node = rowBase + r;
        ushort4 o; o.x = 0; o.y = 0; o.z = 0; o.w = 0;
        if (node < N_NODES) {
            float di = dinv[node];
            ushort4 a = r4[node * 64 + lane];   // self term (prescaled)
            float ax = b2f(a.x), ay = b2f(a.y), az = b2f(a.z), aw = b2f(a.w);
            uint32_t s0 = start[node];
            uint32_t dg = deg[node];
            uint32_t j = 0;
            for (; j + 4 <= dg; j += 4) {
                int i0 = col[s0 + j + 0];
                int i1 = col[s0 + j + 1];
                int i2 = col[s0 + j + 2];
                int i3 = col[s0 + j + 3];
                ushort4 b0 = r4[i0 * 64 + lane];
                ushort4 b1 = r4[i1 * 64 + lane];
                ushort4 b2 = r4[i2 * 64 + lane];
                ushort4 b3 = r4[i3 * 64 + lane];
                ax += b2f(b0.x) + b2f(b1.x) + b2f(b2.x) + b2f(b3.x);
                ay += b2f(b0.y) + b2f(b1.y) + b2f(b2.y) + b2f(b3.y);
                az += b2f(b0.z) + b2f(b1.z) + b2f(b2.z) + b2f(b3.z);
                aw += b2f(b0.w) + b2f(b1.w) + b2f(b2.w) + b2f(b3.w);
            }
            for (; j < dg; ++j) {
                int s = col[s0 + j];
                ushort4 b = r4[s * 64 + lane];
                ax += b2f(b.x); ay += b2f(b.y); az += b2f(b.z); aw += b2f(b.w);
            }
            o.x = f2b(di * ax); o.y = f2b(di * ay);
            o.z = f2b(di * az); o.w = f2b(di * aw);
        }
        *(ushort4*)((char*)As + r * 528 + lane * 8) = o;
    }
    __syncthreads();

    // ---- phase 2: MFMA GEMM from LDS ----
    int quad = lane >> 4;
    int m    = lane & 15;
    int nCol = wave * 64 + m;

    f32x4 acc[4][4];
    #pragma unroll
    for (int mt = 0; mt < 4; ++mt)
        #pragma unroll
        for (int nt = 0; nt < 4; ++nt)
            acc[mt][nt] = (f32x4){0.f, 0.f, 0.f, 0.f};

    #pragma unroll
    for (int ks = 0; ks < 8; ++ks) {          // K = 8 steps x 32
        short8 bfrag[4];
        #pragma unroll
        for (int nt = 0; nt < 4; ++nt)
            bfrag[nt] = *(const short8*)(Wt + (size_t)(nCol + nt * 16) * 256 + ks * 32 + quad * 8);
        short8 afrag[4];
        #pragma unroll
        for (int mt = 0; mt < 4; ++mt)
            afrag[mt] = *(const short8*)((char*)As + (mt * 16 + m) * 528 + ks * 64 + quad * 16);
        #pragma unroll
        for (int mt = 0; mt < 4; ++mt)
            #pragma unroll
            for (int nt = 0; nt < 4; ++nt)
                acc[mt][nt] = __builtin_amdgcn_mfma_f32_16x16x32_bf16(
                    afrag[mt], bfrag[nt], acc[mt][nt], 0, 0, 0);
    }

    // epilogue: C/D layout col=lane&15, row=quad*4+reg
    #pragma unroll
    for (int nt = 0; nt < 4; ++nt) {
        int c = wave * 64 + nt * 16 + m;
        float bv = bias[c];
        #pragma unroll
        for (int mt = 0; mt < 4; ++mt) {
            #pragma unroll
            for (int r = 0; r < 4; ++r) {
                int row = rowBase + mt * 16 + quad * 4 + r;
                if (row < N_NODES) {
                    float v = fmaxf(acc[mt][nt][r] + bv, 0.f);
                    if (Cf) Cf[(size_t)row * 256 + c] = v;
                    else    Cb[(size_t)row * 256 + c] = f2b(dinv[row] * v);
                }
            }
        }
    }
}

extern "C" void kernel_launch(void* const* d_in, const int* in_sizes, int n_in,
                              void* d_out, int out_size, void* d_ws, size_t ws_size,
                              hipStream_t stream) {
    const int*   edge = (const int*)d_in[0];   // [2][E]: row0 = src, row1 = dst
    const float* x    = (const float*)d_in[1];
    const float* W1   = (const float*)d_in[2];
    const float* b1   = (const float*)d_in[3];
    const float* W2   = (const float*)d_in[4];
    const float* b2   = (const float*)d_in[5];
    float* out = (float*)d_out;

    char* ws = (char*)d_ws;
    uint32_t*       deg     = (uint32_t*)(ws + 0);
    uint32_t*       cursor  = (uint32_t*)(ws + 400000);
    uint32_t*       counter = (uint32_t*)(ws + 800000);
    float*          dinv    = (float*)   (ws + 800256);
    uint32_t*       start   = (uint32_t*)(ws + 1200384);
    int*            col     = (int*)     (ws + 1600512);
    unsigned short* Wt1     = (unsigned short*)(ws + 5600512);
    unsigned short* Wt2     = (unsigned short*)(ws + 5731584);
    unsigned short* xs      = (unsigned short*)(ws + 5862656);
    unsigned short* z1s     = (unsigned short*)(ws + 57062656ull);

    const int* src = edge;
    const int* dst = edge + N_EDGES;

    k_zero<<<256, 256, 0, stream>>>((uint32_t*)ws, 2 * N_NODES + 1);
    k_count<<<(N_EDGES + 255) / 256, 256, 0, stream>>>(dst, deg);
    k_dinv_start<<<(N_NODES + 255) / 256, 256, 0, stream>>>(deg, dinv, start, counter);
    k_fill<<<(N_EDGES + 255) / 256, 256, 0, stream>>>(src, dst, start, cursor, col);

    k_pack_w<<<256, 256, 0, stream>>>(W1, Wt1);
    k_pack_w<<<256, 256, 0, stream>>>(W2, Wt2);
    k_cvt_x<<<(N_NODES * DIM / 4) / 256, 256, 0, stream>>>(x, dinv, xs);

    // layer 1: fused gather+gemm, epilogue writes dinv-prescaled z1s (bf16)
    k_fused<<<(N_NODES + 63) / 64, 256, 0, stream>>>(xs, Wt1, b1, dinv,
                                                     start, deg, col, z1s, nullptr);
    // layer 2: fused gather+gemm, epilogue writes fp32 out
    k_fused<<<(N_NODES + 63) / 64, 256, 0, stream>>>(z1s, Wt2, b2, dinv,
                                                     start, deg, col, nullptr, out);
}

// Round 5
// 664.395 us; speedup vs baseline: 1.0650x; 1.0650x over previous
//
#include <hip/hip_runtime.h>
#include <stdint.h>

#define N_NODES 100000
#define N_EDGES 1000000
#define DIM 256
#define E_PAD (N_EDGES + 7 * N_NODES)   // col capacity with per-node pad-to-8

typedef __attribute__((ext_vector_type(8))) short short8;   // bf16 A/B frag (4 VGPR)
typedef __attribute__((ext_vector_type(4))) float f32x4;    // fp32 C/D frag

__device__ inline float b2f(unsigned short u) {
    union { unsigned int i; float f; } v; v.i = ((unsigned int)u) << 16; return v.f;
}
__device__ inline unsigned short f2b(float f) {   // round-to-nearest-even
    union { float f; unsigned int i; } v; v.f = f;
    unsigned int u = v.i;
    return (unsigned short)((u + 0x7FFFu + ((u >> 16) & 1u)) >> 16);
}

// ---------------- workspace layout (bytes) ----------------
// deg     u32 N          @ 0
// cursor  u32 N          @ 400000
// counter u32 1          @ 800000
// dinv    f32 N          @ 800256
// start   u32 N          @ 1200384
// col     i32 E_PAD      @ 1600512   (6.8 MB)
// Wt1     bf16 256x256   @ 8600512
// Wt2     bf16 256x256   @ 8731584
// xs      bf16 (N+1)x256 @ 8862656   (row N = zero pad row)
// z1s     bf16 (N+1)x256 @ 60063168
// agg     bf16 (N+1)x256 @ 111263680 (end ~162.5 MB)

// zero deg/cursor/counter; init col to the zero-row index; zero pad rows
__global__ void k_init(uint32_t* __restrict__ zp, int* __restrict__ col,
                       uint32_t* __restrict__ xpad, uint32_t* __restrict__ zpad,
                       uint32_t* __restrict__ apad) {
    int i = blockIdx.x * blockDim.x + threadIdx.x;
    int stride = gridDim.x * blockDim.x;
    for (int j = i; j < 2 * N_NODES + 1; j += stride) zp[j] = 0u;
    for (int j = i; j < E_PAD; j += stride) col[j] = N_NODES;
    if (i < 128) { xpad[i] = 0u; zpad[i] = 0u; apad[i] = 0u; }
}

__global__ void k_count(const int* __restrict__ dst, uint32_t* __restrict__ deg) {
    int e = blockIdx.x * blockDim.x + threadIdx.x;
    if (e < N_EDGES) {
        unsigned d = (unsigned)dst[e];
        if (d < N_NODES) atomicAdd(&deg[d], 1u);
    }
}

// start[n] = exclusive prefix of pad8(deg); dinv[n] = rsqrt(deg+1)
__global__ void k_dinv_start(const uint32_t* __restrict__ deg,
                             float* __restrict__ dinv,
                             uint32_t* __restrict__ start,
                             uint32_t* __restrict__ counter) {
    int n = blockIdx.x * blockDim.x + threadIdx.x;
    int lane = threadIdx.x & 63;
    int d  = (n < N_NODES) ? (int)deg[n] : 0;
    int pd = (d + 7) & ~7;
    int v = pd;
    #pragma unroll
    for (int off = 1; off < 64; off <<= 1) {
        int t = __shfl_up(v, off, 64);
        if (lane >= off) v += t;
    }
    int total = __shfl(v, 63, 64);
    int base = 0;
    if (lane == 63) base = (int)atomicAdd(counter, (uint32_t)total);
    base = __shfl(base, 63, 64);
    if (n < N_NODES) {
        start[n] = (uint32_t)(base + v - pd);   // exclusive, 8-aligned segments
        dinv[n]  = rsqrtf((float)(d + 1));      // +1 self-loop
    }
}

__global__ void k_fill(const int* __restrict__ src, const int* __restrict__ dst,
                       const uint32_t* __restrict__ start,
                       uint32_t* __restrict__ cursor, int* __restrict__ col) {
    int e = blockIdx.x * blockDim.x + threadIdx.x;
    if (e < N_EDGES) {
        unsigned d = (unsigned)dst[e];
        unsigned s = (unsigned)src[e];
        if (d < N_NODES && s < N_NODES) {
            uint32_t p = atomicAdd(&cursor[d], 1u);
            col[start[d] + p] = (int)s;
        }
    }
}

// W (k-major, [k][n] fp32) -> Wt (n-major, [n][k] bf16)
__global__ void k_pack_w(const float* __restrict__ W, unsigned short* __restrict__ Wt) {
    int n = blockIdx.x, k = threadIdx.x;
    Wt[n * 256 + k] = f2b(W[k * 256 + n]);
}

// xs[row] = bf16( dinv[row] * x[row] )
__global__ void k_cvt_x(const float* __restrict__ x, const float* __restrict__ dinv,
                        unsigned short* __restrict__ xs) {
    int i = blockIdx.x * 256 + threadIdx.x;   // float4 index
    int row = i >> 6;                          // 64 float4 per row
    float di = dinv[row];
    float4 v = ((const float4*)x)[i];
    ushort4 o;
    o.x = f2b(di * v.x); o.y = f2b(di * v.y); o.z = f2b(di * v.z); o.w = f2b(di * v.w);
    ((ushort4*)xs)[i] = o;
}

// agg[i] = bf16( dinv[i] * ( xs[i] + sum_{s in N(i)} xs[s] ) )
// One wave per node, lane = 4 channels (8 B/lane). Segments padded to 8 with
// zero-row indices: branchless x8 unroll, 8 outstanding 512 B fetches/wave.
// start/deg forced scalar so col[] index loads go down the SMEM path.
__global__ __launch_bounds__(256) void k_gather(
        const unsigned short* __restrict__ rows, const float* __restrict__ dinv,
        const uint32_t* __restrict__ start, const uint32_t* __restrict__ deg,
        const int* __restrict__ col, unsigned short* __restrict__ out) {
    int wave = threadIdx.x >> 6;
    int lane = threadIdx.x & 63;
    int node = blockIdx.x * 4 + wave;   // grid = N/4 exactly

    const ushort4* r4 = (const ushort4*)rows;
    float di = dinv[node];
    ushort4 a = r4[node * 64 + lane];   // self term (prescaled)
    float ax = b2f(a.x), ay = b2f(a.y), az = b2f(a.z), aw = b2f(a.w);

    uint32_t s0 = (uint32_t)__builtin_amdgcn_readfirstlane((int)start[node]);
    uint32_t dg = (uint32_t)__builtin_amdgcn_readfirstlane((int)deg[node]);
    uint32_t pd = (dg + 7u) & ~7u;

    for (uint32_t j = 0; j < pd; j += 8) {
        int idx[8];
        #pragma unroll
        for (int t = 0; t < 8; ++t) idx[t] = col[s0 + j + t];
        ushort4 b[8];
        #pragma unroll
        for (int t = 0; t < 8; ++t) b[t] = r4[idx[t] * 64 + lane];
        #pragma unroll
        for (int t = 0; t < 8; ++t) {
            ax += b2f(b[t].x); ay += b2f(b[t].y);
            az += b2f(b[t].z); aw += b2f(b[t].w);
        }
    }
    ushort4 o;
    o.x = f2b(di * ax); o.y = f2b(di * ay); o.z = f2b(di * az); o.w = f2b(di * aw);
    ((ushort4*)out)[node * 64 + lane] = o;
}

// C[64 x 256] = relu(A_tile @ W + b), A frags DIRECT from global (L2/L3-hot,
// written by the preceding gather). No LDS, no barrier — waves independent,
// occupancy VGPR-bound. OOB rows clamp to the zero pad row (row N_NODES).
// Cb!=null -> bf16 store of dinv[row]*relu(...) (layer-2 input);
// else fp32 relu(...) to Cf (final output).
__global__ __launch_bounds__(256, 2) void k_gemm(
        const unsigned short* __restrict__ A, const unsigned short* __restrict__ Wt,
        const float* __restrict__ bias, const float* __restrict__ dinv,
        unsigned short* __restrict__ Cb, float* __restrict__ Cf) {
    int tid = threadIdx.x;
    int wave = tid >> 6, lane = tid & 63;
    int quad = lane >> 4, m = lane & 15;
    int rowBase = blockIdx.x * 64;
    int nCol = wave * 64 + m;

    int rIdx[4];
    #pragma unroll
    for (int mt = 0; mt < 4; ++mt) {
        int gr = rowBase + mt * 16 + m;
        rIdx[mt] = (gr < N_NODES) ? gr : N_NODES;   // zero pad row
    }

    f32x4 acc[4][4];
    #pragma unroll
    for (int mt = 0; mt < 4; ++mt)
        #pragma unroll
        for (int nt = 0; nt < 4; ++nt)
            acc[mt][nt] = (f32x4){0.f, 0.f, 0.f, 0.f};

    #pragma unroll
    for (int ks = 0; ks < 8; ++ks) {          // K = 8 steps x 32
        short8 bfrag[4];
        #pragma unroll
        for (int nt = 0; nt < 4; ++nt)
            bfrag[nt] = *(const short8*)(Wt + (size_t)(nCol + nt * 16) * 256 + ks * 32 + quad * 8);
        short8 afrag[4];
        #pragma unroll
        for (int mt = 0; mt < 4; ++mt)
            afrag[mt] = *(const short8*)(A + (size_t)rIdx[mt] * 256 + ks * 32 + quad * 8);
        #pragma unroll
        for (int mt = 0; mt < 4; ++mt)
            #pragma unroll
            for (int nt = 0; nt < 4; ++nt)
                acc[mt][nt] = __builtin_amdgcn_mfma_f32_16x16x32_bf16(
                    afrag[mt], bfrag[nt], acc[mt][nt], 0, 0, 0);
    }

    // epilogue: C/D layout col=lane&15, row=quad*4+reg
    #pragma unroll
    for (int nt = 0; nt < 4; ++nt) {
        int c = wave * 64 + nt * 16 + m;
        float bv = bias[c];
        #pragma unroll
        for (int mt = 0; mt < 4; ++mt) {
            #pragma unroll
            for (int r = 0; r < 4; ++r) {
                int row = rowBase + mt * 16 + quad * 4 + r;
                if (row < N_NODES) {
                    float v = fmaxf(acc[mt][nt][r] + bv, 0.f);
                    if (Cf) Cf[(size_t)row * 256 + c] = v;
                    else    Cb[(size_t)row * 256 + c] = f2b(dinv[row] * v);
                }
            }
        }
    }
}

extern "C" void kernel_launch(void* const* d_in, const int* in_sizes, int n_in,
                              void* d_out, int out_size, void* d_ws, size_t ws_size,
                              hipStream_t stream) {
    const int*   edge = (const int*)d_in[0];   // [2][E]: row0 = src, row1 = dst
    const float* x    = (const float*)d_in[1];
    const float* W1   = (const float*)d_in[2];
    const float* b1   = (const float*)d_in[3];
    const float* W2   = (const float*)d_in[4];
    const float* b2   = (const float*)d_in[5];
    float* out = (float*)d_out;

    char* ws = (char*)d_ws;
    uint32_t*       deg     = (uint32_t*)(ws + 0);
    uint32_t*       counter = (uint32_t*)(ws + 800000);
    float*          dinv    = (float*)   (ws + 800256);
    uint32_t*       start   = (uint32_t*)(ws + 1200384);
    int*            col     = (int*)     (ws + 1600512);
    unsigned short* Wt1     = (unsigned short*)(ws + 8600512);
    unsigned short* Wt2     = (unsigned short*)(ws + 8731584);
    unsigned short* xs      = (unsigned short*)(ws + 8862656);
    unsigned short* z1s     = (unsigned short*)(ws + 60063168ull);
    unsigned short* agg     = (unsigned short*)(ws + 111263680ull);
    uint32_t*       cursor  = (uint32_t*)(ws + 400000);

    const int* src = edge;
    const int* dst = edge + N_EDGES;

    k_init<<<512, 256, 0, stream>>>((uint32_t*)ws, col,
                                    (uint32_t*)(xs  + (size_t)N_NODES * 256),
                                    (uint32_t*)(z1s + (size_t)N_NODES * 256),
                                    (uint32_t*)(agg + (size_t)N_NODES * 256));
    k_count<<<(N_EDGES + 255) / 256, 256, 0, stream>>>(dst, deg);
    k_dinv_start<<<(N_NODES + 255) / 256, 256, 0, stream>>>(deg, dinv, start, counter);
    k_fill<<<(N_EDGES + 255) / 256, 256, 0, stream>>>(src, dst, start, cursor, col);

    k_pack_w<<<256, 256, 0, stream>>>(W1, Wt1);
    k_pack_w<<<256, 256, 0, stream>>>(W2, Wt2);
    k_cvt_x<<<(N_NODES * DIM / 4) / 256, 256, 0, stream>>>(x, dinv, xs);

    // layer 1: gather (padded x8) -> agg; gemm writes dinv-prescaled z1s (bf16)
    k_gather<<<N_NODES / 4, 256, 0, stream>>>(xs, dinv, start, deg, col, agg);
    k_gemm<<<(N_NODES + 63) / 64, 256, 0, stream>>>(agg, Wt1, b1, dinv, z1s, nullptr);
    // layer 2
    k_gather<<<N_NODES / 4, 256, 0, stream>>>(z1s, dinv, start, deg, col, agg);
    k_gemm<<<(N_NODES + 63) / 64, 256, 0, stream>>>(agg, Wt2, b2, dinv, nullptr, out);
}